// Round 4
// baseline (665.552 us; speedup 1.0000x reference)
//
#include <hip/hip_runtime.h>
#include <cstdint>

#define ENC_DEPTH 8
#define RAYS 64
#define THREADS 256

typedef __attribute__((ext_vector_type(8))) short bf16x8;
typedef __attribute__((ext_vector_type(4))) float f32x4;

__device__ __forceinline__ unsigned short f2bf(float x) {
    union { float f; unsigned u; } v; v.f = x;
    unsigned r = v.u + 0x7fffu + ((v.u >> 16) & 1u);
    return (unsigned short)(r >> 16);
}
__device__ __forceinline__ float bf2f(unsigned short h) {
    union { unsigned u; float f; } v; v.u = ((unsigned)h) << 16;
    return v.f;
}
__device__ __forceinline__ float clamp01(float x) {
    return fminf(fmaxf(x, 0.0f), 1.0f);
}
__device__ __forceinline__ void async_copy16(const void* g, void* l) {
    __builtin_amdgcn_global_load_lds(
        (const __attribute__((address_space(1))) void*)g,
        (__attribute__((address_space(3))) void*)l, 16, 0, 0);
}

// s_waitcnt imm: vmcnt[3:0]=bits3:0, expcnt=bits6:4, lgkmcnt=bits11:8, vmcnt[5:4]=bits15:14
#define WAIT_VMCNT_8() __builtin_amdgcn_s_waitcnt(0xF78)   // vmcnt(8), lgkm/exp no-wait
#define WAIT_VMCNT_0() __builtin_amdgcn_s_waitcnt(0xF70)   // vmcnt(0)

// ---- emb fp32 (N_NODES x 128) -> bf16 table in ws ----
__global__ void emb_bf16_kernel(const float* __restrict__ emb,
                                unsigned short* __restrict__ emb2) {
    size_t i = ((size_t)blockIdx.x * 256 + threadIdx.x) * 8;
    float4 a = *(const float4*)(emb + i);
    float4 b = *(const float4*)(emb + i + 4);
    bf16x8 v;
    v[0] = (short)f2bf(a.x); v[1] = (short)f2bf(a.y);
    v[2] = (short)f2bf(a.z); v[3] = (short)f2bf(a.w);
    v[4] = (short)f2bf(b.x); v[5] = (short)f2bf(b.y);
    v[6] = (short)f2bf(b.z); v[7] = (short)f2bf(b.w);
    *(bf16x8*)(emb2 + i) = v;
}

// ---- W1 (1024x64 fp32) -> fragment-major bf16 ----
__global__ void w1_frag_kernel(const float* __restrict__ W1,
                               unsigned short* __restrict__ W1F) {
    int slot = blockIdx.x * 256 + threadIdx.x;   // 8192 slots
    int lane = slot & 63, tile = (slot >> 6) & 3, kk = (slot >> 8) & 3, d = slot >> 10;
    int n = tile * 16 + (lane & 15);
    int kbase = d * 128 + kk * 32 + (lane >> 4) * 8;
    bf16x8 v;
    #pragma unroll
    for (int j = 0; j < 8; ++j) v[j] = (short)f2bf(W1[(size_t)(kbase + j) * 64 + n]);
    *(bf16x8*)(W1F + (size_t)slot * 8) = v;
}

// Barrier-free wave-private pipelined kernel.
// LDS cbuf: 4 depth-buffers x [wave][group 0..3][1040 B]  (group = 4 rays x 256 B + 16 pad)
//   buf stride 16640 B, wave stride 4160 B. Total 66560 B.
__global__ __launch_bounds__(THREADS, 2) void nbvh4(
    const float* __restrict__ orig, const float* __restrict__ endp,
    const int* __restrict__ hist, const float* __restrict__ nodes_min,
    const float* __restrict__ nodes_extent, const unsigned short* __restrict__ EMB2,
    const unsigned short* __restrict__ W1F, const float* __restrict__ W2,
    const float* __restrict__ W3, float* __restrict__ out)
{
    __shared__ __align__(16) unsigned short cbuf[33280];   // 66560 B
    __shared__ float pope_s[RAYS * ENC_DEPTH * 6];         // 12288 B
    __shared__ int hist_s[RAYS * ENC_DEPTH];               // 2048 B

    const int t = threadIdx.x;
    const int lane = t & 63, w = t >> 6;
    const int r0 = blockIdx.x * RAYS;

    // ---- wave-private history staging (no barrier needed) ----
    hist_s[w * 128 + lane]      = hist[(r0 + w * 16) * 8 + lane];
    hist_s[w * 128 + 64 + lane] = hist[(r0 + w * 16) * 8 + 64 + lane];

    // ---- wave-private po/pe precompute: 16 rays x 8 depths ----
    // (pope global loads issued BEFORE corner DMAs -> their waits don't drain DMAs)
    float pv[2][6];
    int tasks[2];
    #pragma unroll
    for (int rep = 0; rep < 2; ++rep) {
        int task = rep * 64 + lane;          // task = rw*8 + d
        tasks[rep] = task;
        int rw = task >> 3;
        int node = hist_s[w * 128 + task];
        float nm0 = nodes_min[node * 3 + 0], nm1 = nodes_min[node * 3 + 1], nm2 = nodes_min[node * 3 + 2];
        float ex0 = nodes_extent[node * 3 + 0], ex1 = nodes_extent[node * 3 + 1], ex2 = nodes_extent[node * 3 + 2];
        int gr = r0 + w * 16 + rw;
        float o0 = orig[gr * 3 + 0], o1 = orig[gr * 3 + 1], o2 = orig[gr * 3 + 2];
        float e0 = endp[gr * 3 + 0], e1 = endp[gr * 3 + 1], e2 = endp[gr * 3 + 2];
        pv[rep][0] = clamp01((o0 - nm0) / ex0);
        pv[rep][1] = clamp01((o1 - nm1) / ex1);
        pv[rep][2] = clamp01((o2 - nm2) / ex2);
        pv[rep][3] = clamp01((e0 - nm0) / ex0);
        pv[rep][4] = clamp01((e1 - nm1) / ex1);
        pv[rep][5] = clamp01((e2 - nm2) / ex2);
    }

    // ---- DMA issue for one depth (wave-private rays) ----
    auto issue_depth = [&](int d) {
        char* base = (char*)cbuf + (d & 3) * 16640 + w * 4160;
        #pragma unroll
        for (int r = 0; r < 4; ++r) {
            int rw = r * 4 + (lane >> 4);
            int node = hist_s[w * 128 + rw * 8 + d];
            const char* g = (const char*)EMB2 + ((size_t)node << 8) + ((lane & 15) << 4);
            async_copy16(g, base + r * 1040 + lane * 16);
        }
    };
    issue_depth(0);
    issue_depth(1);

    // commit pope to LDS (uses pope-load results: compiler waits vmcnt(8), keeping DMAs)
    #pragma unroll
    for (int rep = 0; rep < 2; ++rep) {
        float* pp = pope_s + w * 768 + tasks[rep] * 6;
        #pragma unroll
        for (int i = 0; i < 6; ++i) pp[i] = pv[rep][i];
    }

    f32x4 acc[4];
    #pragma unroll
    for (int i = 0; i < 4; ++i) acc[i] = (f32x4){0.f, 0.f, 0.f, 0.f};

    const int c = lane & 15, q = lane >> 4;
    const int qh = q & 1;                    // feature half
    const int qp = q >> 1;                   // point offset

    // per-depth compute: interp -> A-frags -> MFMA
    auto compute_depth = [&](int d, const bf16x8* bfr) {
        const float* pp = pope_s + w * 768 + (c * 8 + d) * 6;
        float po0 = pp[0], po1 = pp[1], po2 = pp[2], pe0 = pp[3], pe1 = pp[4], pe2 = pp[5];
        float X[4], OX[4], Y[4], OY[4], Z[4], OZ[4];
        #pragma unroll
        for (int kk = 0; kk < 4; ++kk) {
            float tp = (float)(2 * kk + qp) * (1.0f / 7.0f);
            X[kk] = po0 + (pe0 - po0) * tp; OX[kk] = 1.f - X[kk];
            Y[kk] = po1 + (pe1 - po1) * tp; OY[kk] = 1.f - Y[kk];
            Z[kk] = po2 + (pe2 - po2) * tp; OZ[kk] = 1.f - Z[kk];
        }
        float fa[4][8];
        #pragma unroll
        for (int kk = 0; kk < 4; ++kk)
            #pragma unroll
            for (int j = 0; j < 8; ++j) fa[kk][j] = 0.f;

        const char* cb = (const char*)cbuf + (d & 3) * 16640 + w * 4160
                         + (c >> 2) * 1040 + (c & 3) * 256 + qh * 16;
        #pragma unroll
        for (int j = 0; j < 8; ++j) {
            int c8 = j ^ (c & 3);
            bf16x8 cv = *(const bf16x8*)(cb + c8 * 32);
            float e[8];
            #pragma unroll
            for (int i = 0; i < 8; ++i) e[i] = bf2f((unsigned short)cv[i]);
            #pragma unroll
            for (int kk = 0; kk < 4; ++kk) {
                float wx = ((0xD2 >> c8) & 1) ? X[kk] : OX[kk];
                float wy = ((0xE4 >> c8) & 1) ? Y[kk] : OY[kk];
                float wz = ((0xB8 >> c8) & 1) ? Z[kk] : OZ[kk];
                float wgt = wx * wy * wz;
                #pragma unroll
                for (int i = 0; i < 8; ++i)
                    fa[kk][i] = fmaf(wgt, e[i], fa[kk][i]);
            }
        }
        #pragma unroll
        for (int kk = 0; kk < 4; ++kk) {
            bf16x8 af;
            #pragma unroll
            for (int j = 0; j < 8; ++j) af[j] = (short)f2bf(fa[kk][j]);
            #pragma unroll
            for (int tile = 0; tile < 4; ++tile)
                acc[tile] = __builtin_amdgcn_mfma_f32_16x16x32_bf16(af, bfr[kk * 4 + tile], acc[tile], 0, 0, 0);
        }
    };

    // ---- barrier-free K-loop, unroll 2, prefetch 2-3 depths ahead ----
    #pragma unroll 1
    for (int dd = 0; dd < 8; dd += 2) {
        // B fragments for both depths FIRST (older than the DMAs issued below,
        // so waiting for them never drains the prefetch queue)
        bf16x8 bfr[2][16];
        #pragma unroll
        for (int h = 0; h < 2; ++h)
            #pragma unroll
            for (int f = 0; f < 16; ++f)
                bfr[h][f] = *(const bf16x8*)(W1F + ((size_t)(((dd + h) * 16 + f) * 64 + lane)) * 8);
        if (dd + 2 < 8) { issue_depth(dd + 2); issue_depth(dd + 3); }
        // retire everything except the 8 just-issued prefetch DMAs
        if (dd < 6) WAIT_VMCNT_8(); else WAIT_VMCNT_0();
        compute_depth(dd, bfr[0]);
        compute_depth(dd + 1, bfr[1]);
    }

    // ---- epilogue (single barrier) ----
    float* h1 = (float*)cbuf;                 // 64 x 65 fp32 = 16640 B
    float* h2 = h1 + 4160;                    // 64 x 65 fp32
    #pragma unroll
    for (int tile = 0; tile < 4; ++tile)
        #pragma unroll
        for (int r = 0; r < 4; ++r)
            h1[(w * 16 + q * 4 + r) * 65 + tile * 16 + c] = fmaxf(acc[tile][r], 0.f);
    __syncthreads();

    // GEMM2: h2 = relu(h1 @ W2), fp32 VALU
    {
        int ray2 = t >> 2, jg = (t & 3) << 4;
        float s[16];
        #pragma unroll
        for (int j = 0; j < 16; ++j) s[j] = 0.f;
        const float* hrow = h1 + ray2 * 65;
        #pragma unroll 4
        for (int i = 0; i < 64; ++i) {
            float hv = hrow[i];
            const float4* wr = (const float4*)(W2 + (i << 6) + jg);
            float4 a0 = wr[0], a1 = wr[1], a2 = wr[2], a3 = wr[3];
            s[0]  = fmaf(hv, a0.x, s[0]);  s[1]  = fmaf(hv, a0.y, s[1]);
            s[2]  = fmaf(hv, a0.z, s[2]);  s[3]  = fmaf(hv, a0.w, s[3]);
            s[4]  = fmaf(hv, a1.x, s[4]);  s[5]  = fmaf(hv, a1.y, s[5]);
            s[6]  = fmaf(hv, a1.z, s[6]);  s[7]  = fmaf(hv, a1.w, s[7]);
            s[8]  = fmaf(hv, a2.x, s[8]);  s[9]  = fmaf(hv, a2.y, s[9]);
            s[10] = fmaf(hv, a2.z, s[10]); s[11] = fmaf(hv, a2.w, s[11]);
            s[12] = fmaf(hv, a3.x, s[12]); s[13] = fmaf(hv, a3.y, s[13]);
            s[14] = fmaf(hv, a3.z, s[14]); s[15] = fmaf(hv, a3.w, s[15]);
        }
        float* h2row = h2 + ray2 * 65 + jg;
        #pragma unroll
        for (int j = 0; j < 16; ++j) h2row[j] = fmaxf(s[j], 0.f);
    }
    __syncthreads();

    // GEMM3 + output
    if (t < 128) {
        int ray3 = t >> 1, cc = t & 1;
        const float* hrow = h2 + ray3 * 65;
        float a = 0.f;
        #pragma unroll 16
        for (int i = 0; i < 64; ++i) a = fmaf(hrow[i], W3[i * 2 + cc], a);
        if (cc) {
            float dx = endp[(r0 + ray3) * 3 + 0] - orig[(r0 + ray3) * 3 + 0];
            float dy = endp[(r0 + ray3) * 3 + 1] - orig[(r0 + ray3) * 3 + 1];
            float dz = endp[(r0 + ray3) * 3 + 2] - orig[(r0 + ray3) * 3 + 2];
            a *= sqrtf(dx * dx + dy * dy + dz * dz);
        }
        out[((r0 + ray3) << 1) + cc] = a;
    }
}

extern "C" void kernel_launch(void* const* d_in, const int* in_sizes, int n_in,
                              void* d_out, int out_size, void* d_ws, size_t ws_size,
                              hipStream_t stream) {
    const float* orig = (const float*)d_in[0];
    const float* endp = (const float*)d_in[1];
    const int*   hist = (const int*)d_in[2];
    const float* nmin = (const float*)d_in[3];
    const float* next = (const float*)d_in[4];
    const float* emb  = (const float*)d_in[5];
    const float* W1   = (const float*)d_in[6];
    const float* W2   = (const float*)d_in[7];
    const float* W3   = (const float*)d_in[8];
    float* out = (float*)d_out;

    const int n_nodes = in_sizes[5] / 128;               // 524288
    const size_t emb2_bytes = (size_t)n_nodes * 128 * 2; // 128 MB
    const int n_rays = in_sizes[0] / 3;

    unsigned short* EMB2 = (unsigned short*)d_ws;
    unsigned short* W1F = (unsigned short*)((char*)d_ws + emb2_bytes);

    emb_bf16_kernel<<<dim3((n_nodes * 128) / (256 * 8)), dim3(256), 0, stream>>>(emb, EMB2);
    w1_frag_kernel<<<dim3(32), dim3(256), 0, stream>>>(W1, W1F);
    nbvh4<<<dim3(n_rays / RAYS), dim3(THREADS), 0, stream>>>(
        orig, endp, hist, nmin, next, EMB2, W1F, W2, W3, out);
}